// Round 7
// baseline (239.103 us; speedup 1.0000x reference)
//
#include <hip/hip_runtime.h>
#include <math.h>

#define N_ANCHORS 2048
#define BLOCK 512
#define THRESH 0.3f
#define OVERLAP 0.5f

// Manual LDS pool: stage A (compacted, anchor order) then stage B (sorted
// order) alias the same bytes; handoff goes through registers + a barrier.
#define OFF_CSC   0        // float[2052]   stage A  (8208 B)
#define OFF_CBX   8208     // float2[2048]  stage A  (16384 B)
#define OFF_CID   24592    // ushort[2048]  stage A  (4096 B)
#define OFF_SBOX  0        // float2[2112]  stage B  (16896 B)
#define OFF_SSC   16896    // float[2048]   stage B  (8192 B)
#define OFF_SID   25088    // ushort[2048]  stage B  (4096 B)
#define POOL_SZ   29184

#define TRI(k, w) ((k) * ((k) + 1) / 2 + (w))   // triangular row storage

__global__ __launch_bounds__(BLOCK) void det_kernel(
    const float* __restrict__ loc,    // (8, 2048, 2)
    const float* __restrict__ cls,    // (8, 2048, 5)
    const float* __restrict__ defs,   // (2048, 2)
    float* __restrict__ out)          // (8, 4, 2048, 3)
{
#pragma clang fp contract(off)
    const int tid  = threadIdx.x;
    const int lane = tid & 63;
    const int wid  = tid >> 6;        // 0..7
    const int bc   = blockIdx.x;      // 0..31
    const int b    = bc >> 2;
    const int c    = bc & 3;          // softmax component c+1

    __shared__ __align__(16) unsigned char pool[POOL_SZ];
    // transposed: suprowT[w*512 + u] = word w of box u's suppression row
    __shared__ __align__(16) unsigned long long suprowT[8 * 512];   // 32 KB
    __shared__ unsigned long long keptg[32];    // kept bits, global sorted pos
    __shared__ unsigned long long s_deadw[8];   // cross-superchunk dead words
    __shared__ int s_wsum[8], s_woff[8], s_V;

    float*          csc  = (float*)(pool + OFF_CSC);
    float2*         cbx  = (float2*)(pool + OFF_CBX);
    unsigned short* cid  = (unsigned short*)(pool + OFF_CID);
    float2*         sbox = (float2*)(pool + OFF_SBOX);
    float*          ssc  = (float*)(pool + OFF_SSC);
    unsigned short* sid  = (unsigned short*)(pool + OFF_SID);

    // ---- Phase 0: zero output (fire-and-forget; barriers drain vmcnt) ----
    float* const outb = out + (size_t)bc * N_ANCHORS * 3;
    {
        float4 z4 = make_float4(0.f, 0.f, 0.f, 0.f);
        float4* ob4 = (float4*)outb;
        for (int i = tid; i < (N_ANCHORS * 3) / 4; i += BLOCK) ob4[i] = z4;
    }
    if (tid < 32) keptg[tid] = 0ull;

    // ---- Phase 1: float4 loads + softmax + decode, 4 consecutive anchors ----
    const int base = tid * 4;
    float c20[20], l8v[8], d8v[8];
    {
        const float4* cp4 = (const float4*)(cls + ((size_t)b * N_ANCHORS + base) * 5);
#pragma unroll
        for (int q = 0; q < 5; ++q) ((float4*)c20)[q] = cp4[q];
        const float4* lp4 = (const float4*)(loc + ((size_t)b * N_ANCHORS + base) * 2);
        ((float4*)l8v)[0] = lp4[0]; ((float4*)l8v)[1] = lp4[1];
        const float4* dp4 = (const float4*)(defs + (size_t)base * 2);
        ((float4*)d8v)[0] = dp4[0]; ((float4*)d8v)[1] = dp4[1];
    }
    float sc4[4], bs4[4], be4[4];
    int vmask = 0, cnt = 0;
#pragma unroll
    for (int k = 0; k < 4; ++k) {
        float x0 = c20[5*k+0], x1 = c20[5*k+1], x2 = c20[5*k+2],
              x3 = c20[5*k+3], x4 = c20[5*k+4];
        float m  = fmaxf(fmaxf(fmaxf(fmaxf(x0, x1), x2), x3), x4);
        float e0 = expf(x0 - m), e1 = expf(x1 - m), e2 = expf(x2 - m),
              e3 = expf(x3 - m), e4 = expf(x4 - m);
        float sum = e0 + e1 + e2 + e3 + e4;
        float ec  = (c == 0) ? e1 : (c == 1) ? e2 : (c == 2) ? e3 : e4;
        float score = ec / sum;
        float l0 = l8v[2*k], l1 = l8v[2*k+1];
        float d0 = d8v[2*k], d1 = d8v[2*k+1];
        float cc = d0 + l0 * d1;
        float w  = d1 * expf(l1);
        sc4[k] = score;
        bs4[k] = cc - 0.5f * w;
        be4[k] = cc + 0.5f * w;
        if (score > THRESH) { vmask |= (1 << k); cnt++; }
    }

    // ---- ordered compaction (compacted order == anchor order) ----
    int inc = cnt;
    for (int d = 1; d < 64; d <<= 1) {
        int v = __shfl_up(inc, d);
        if (lane >= d) inc += v;
    }
    if (lane == 63) s_wsum[wid] = inc;
    __syncthreads();
    if (tid == 0) {
        int o = 0;
        for (int w = 0; w < 8; ++w) { s_woff[w] = o; o += s_wsum[w]; }
        s_V = o;
    }
    __syncthreads();
    {
        int off = s_woff[wid] + (inc - cnt);
#pragma unroll
        for (int k = 0; k < 4; ++k) {
            if (vmask & (1 << k)) {
                csc[off] = sc4[k];
                cbx[off] = make_float2(bs4[k], be4[k]);
                cid[off] = (unsigned short)(base + k);
                off++;
            }
        }
    }
    __syncthreads();
    const int V = s_V;
    const int SCend = ((V + 511) >> 9) << 9;   // pad to super-chunk boundary
    if (tid < 4) csc[V + tid] = -INFINITY;     // pad for float4 rank stream
    __syncthreads();

    // ---- Phase 2: counting rank (score desc, anchor-order asc on ties) ----
    // Gather to REGISTERS before stage-B overwrites stage-A bytes.
    // 4-batched LDS reads keep 4 loads in flight (cuts exposed latency 4x).
#define RANKCMP(sv, ib, off2, mref, rref)                                   \
    rref += ((sv) > (mref) || ((sv) == (mref) && (ib) + (off2) < pcmp)) ? 1 : 0;
    int rr[4]; float2 rb[4]; float rs[4]; int ridv[4]; int nown = 0;
    if (V <= 512) {
        if (tid < 256) {
            int   p0 = tid, p1 = tid + 256;
            bool  a0 = p0 < V, a1 = p1 < V;
            float m0 = a0 ? csc[p0] : INFINITY;
            float m1 = a1 ? csc[p1] : INFINITY;
            int   r0 = 0, r1 = 0;
            const float4* cs4 = (const float4*)csc;
            const int n4 = (V + 3) >> 2;
            int i4 = 0;
            for (; i4 + 4 <= n4; i4 += 4) {
                float4 q0 = cs4[i4+0], q1 = cs4[i4+1], q2 = cs4[i4+2], q3 = cs4[i4+3];
                int ib = i4 << 2;
                { int pcmp = p0;
                  RANKCMP(q0.x, ib, 0,  m0, r0) RANKCMP(q0.y, ib, 1,  m0, r0)
                  RANKCMP(q0.z, ib, 2,  m0, r0) RANKCMP(q0.w, ib, 3,  m0, r0)
                  RANKCMP(q1.x, ib, 4,  m0, r0) RANKCMP(q1.y, ib, 5,  m0, r0)
                  RANKCMP(q1.z, ib, 6,  m0, r0) RANKCMP(q1.w, ib, 7,  m0, r0)
                  RANKCMP(q2.x, ib, 8,  m0, r0) RANKCMP(q2.y, ib, 9,  m0, r0)
                  RANKCMP(q2.z, ib, 10, m0, r0) RANKCMP(q2.w, ib, 11, m0, r0)
                  RANKCMP(q3.x, ib, 12, m0, r0) RANKCMP(q3.y, ib, 13, m0, r0)
                  RANKCMP(q3.z, ib, 14, m0, r0) RANKCMP(q3.w, ib, 15, m0, r0) }
                { int pcmp = p1;
                  RANKCMP(q0.x, ib, 0,  m1, r1) RANKCMP(q0.y, ib, 1,  m1, r1)
                  RANKCMP(q0.z, ib, 2,  m1, r1) RANKCMP(q0.w, ib, 3,  m1, r1)
                  RANKCMP(q1.x, ib, 4,  m1, r1) RANKCMP(q1.y, ib, 5,  m1, r1)
                  RANKCMP(q1.z, ib, 6,  m1, r1) RANKCMP(q1.w, ib, 7,  m1, r1)
                  RANKCMP(q2.x, ib, 8,  m1, r1) RANKCMP(q2.y, ib, 9,  m1, r1)
                  RANKCMP(q2.z, ib, 10, m1, r1) RANKCMP(q2.w, ib, 11, m1, r1)
                  RANKCMP(q3.x, ib, 12, m1, r1) RANKCMP(q3.y, ib, 13, m1, r1)
                  RANKCMP(q3.z, ib, 14, m1, r1) RANKCMP(q3.w, ib, 15, m1, r1) }
            }
            for (; i4 < n4; ++i4) {
                float4 s4 = cs4[i4];
                int ib = i4 << 2;
                { int pcmp = p0;
                  RANKCMP(s4.x, ib, 0, m0, r0) RANKCMP(s4.y, ib, 1, m0, r0)
                  RANKCMP(s4.z, ib, 2, m0, r0) RANKCMP(s4.w, ib, 3, m0, r0) }
                { int pcmp = p1;
                  RANKCMP(s4.x, ib, 0, m1, r1) RANKCMP(s4.y, ib, 1, m1, r1)
                  RANKCMP(s4.z, ib, 2, m1, r1) RANKCMP(s4.w, ib, 3, m1, r1) }
            }
            if (a0) { rr[nown] = r0; rb[nown] = cbx[p0]; rs[nown] = m0; ridv[nown] = cid[p0]; nown++; }
            if (a1) { rr[nown] = r1; rb[nown] = cbx[p1]; rs[nown] = m1; ridv[nown] = cid[p1]; nown++; }
        }
    } else {
        for (int p = tid; p < V; p += BLOCK) {
            float s = csc[p];
            int r = 0;
            const float4* cs4 = (const float4*)csc;
            const int n4 = (V + 3) >> 2;
            for (int i4 = 0; i4 < n4; ++i4) {
                float4 s4 = cs4[i4];
                int ib = i4 << 2;
                int pcmp = p;
                RANKCMP(s4.x, ib, 0, s, r) RANKCMP(s4.y, ib, 1, s, r)
                RANKCMP(s4.z, ib, 2, s, r) RANKCMP(s4.w, ib, 3, s, r)
            }
            rr[nown] = r; rb[nown] = cbx[p]; rs[nown] = s; ridv[nown] = cid[p]; nown++;
        }
    }
#undef RANKCMP
    __syncthreads();   // all stage-A reads done
    for (int q = 0; q < nown; ++q) {
        sbox[rr[q]] = rb[q];
        ssc[rr[q]]  = rs[q];
        sid[rr[q]]  = (unsigned short)ridv[q];
    }
    for (int i = V + tid; i < SCend; i += BLOCK)
        sbox[i] = make_float2(1e30f, 1e30f);   // inert pad (IoU == 0, incl. pad-pad)
    __syncthreads();

    // ---- Phase 3: super-chunks of 512 sorted boxes (one pass when V<=512) ----
    for (int s0 = 0; s0 < V; s0 += 512) {
        const int scn = (V - s0 < 512) ? (V - s0) : 512;
        const int i   = tid;                 // box index within super-chunk
        float2 my = sbox[s0 + i];            // pads are inert
        float  ml = my.y - my.x;

        // (a) dead from earlier super-chunks' kept (no-op when s0 == 0)
        bool dead = false;
        const int ew_n = s0 >> 6;
        for (int ew = 0; ew < ew_n; ++ew) {
            unsigned long long kw = keptg[ew];   // wave-uniform
            if (kw) {
                const float4* sb4 = (const float4*)(sbox + (ew << 6));
#pragma unroll
                for (int jj = 0; jj < 32; ++jj) {
                    float4 bp = sb4[jj];
                    float in0 = fmaxf(fminf(my.y, bp.y) - fmaxf(my.x, bp.x), 0.0f);
                    float un0 = (bp.y - bp.x) + ml - in0;
                    float io0 = in0 / fmaxf(un0, 1e-12f);
                    float in1 = fmaxf(fminf(my.y, bp.w) - fmaxf(my.x, bp.z), 0.0f);
                    float un1 = (bp.w - bp.z) + ml - in1;
                    float io1 = in1 / fmaxf(un1, 1e-12f);
                    unsigned long long bits = kw >> (2 * jj);
                    dead |= (io0 > OVERLAP) && ((bits & 1ull) != 0ull);
                    dead |= (io1 > OVERLAP) && ((bits & 2ull) != 0ull);
                }
            }
        }
        {
            unsigned long long db = __ballot(dead && (i < scn));
            if (lane == 0) s_deadw[wid] = db;
        }

        // (b) build suppression rows, TRANSPOSED, REBALANCED: the 36 (k,w)
        // units spread round-robin over 8 waves (max 5 units/wave vs 8).
        {
            int t = 0;
#pragma unroll
            for (int k = 0; k < 8; ++k) {
#pragma unroll
                for (int w = 0; w <= k; ++w, ++t) {
                    if ((t & 7) == wid) {
                        const int u = (k << 6) + lane;   // row this lane builds
                        float2 ub = sbox[s0 + u];        // lane-distinct b64
                        float  ul = ub.y - ub.x;
                        const float4* sb4 = (const float4*)(sbox + s0 + (w << 6));
                        unsigned long long word = 0ull;
#pragma unroll
                        for (int jj = 0; jj < 32; ++jj) {
                            float4 bp = sb4[jj];
                            float in0 = fmaxf(fminf(ub.y, bp.y) - fmaxf(ub.x, bp.x), 0.0f);
                            float un0 = (bp.y - bp.x) + ul - in0;
                            float io0 = in0 / fmaxf(un0, 1e-12f);
                            float in1 = fmaxf(fminf(ub.y, bp.w) - fmaxf(ub.x, bp.z), 0.0f);
                            float un1 = (bp.w - bp.z) + ul - in1;
                            float io1 = in1 / fmaxf(un1, 1e-12f);
                            int j0 = (w << 6) + 2 * jj;
                            if (io0 > OVERLAP && j0     < u) word |= (1ull << (2 * jj));
                            if (io1 > OVERLAP && j0 + 1 < u) word |= (1ull << (2 * jj + 1));
                        }
                        suprowT[(w << 9) + u] = word;
                    }
                }
            }
        }
        __syncthreads();

        // (c) wave 0: register-resident greedy fixpoint. No LDS, no barriers
        // in the loop; 2 ballots per DAG level.
        if (wid == 0) {
            unsigned long long row[36];
#pragma unroll
            for (int k = 0; k < 8; ++k)
#pragma unroll
                for (int w = 0; w <= k; ++w)
                    row[TRI(k, w)] = suprowT[(w << 9) + (k << 6) + lane];
            unsigned long long sdead[8];
#pragma unroll
            for (int w = 0; w < 8; ++w) sdead[w] = s_deadw[w];

            unsigned long long kv[8];
#pragma unroll
            for (int w = 0; w < 8; ++w) {
                kv[w] = 0ull;
                if ((w << 6) < scn) {
                    bool dl = ((sdead[w] >> lane) & 1ull) != 0ull;
#pragma unroll
                    for (int w2 = 0; w2 < w; ++w2)
                        dl |= (row[TRI(w, w2)] & kv[w2]) != 0ull;
                    const unsigned long long rself = row[TRI(w, w)];
                    int rem = scn - (w << 6);
                    unsigned long long valid =
                        (rem >= 64) ? ~0ull : ((1ull << rem) - 1ull);
                    unsigned long long cand = valid & ~__ballot(dl);
                    unsigned long long kw = 0ull;
                    while (cand) {
                        unsigned long long suppw = __ballot((rself & cand) != 0ull);
                        unsigned long long nk = cand & ~suppw;
                        if (!nk) nk = cand & (~cand + 1ull);  // acyclic: unreachable
                        kw |= nk;
                        unsigned long long ddw = __ballot((rself & nk) != 0ull);
                        cand &= ~(nk | ddw);
                    }
                    kv[w] = kw;
                }
            }
            if (lane == 0) {
#pragma unroll
                for (int w = 0; w < 8; ++w) keptg[(s0 >> 6) + w] |= kv[w];
            }
        }
        __syncthreads();
    }

    // ---- Phase 4: scatter kept (in_range applied at output only) ----
    for (int r = tid; r < V; r += BLOCK) {
        if ((keptg[r >> 6] >> (r & 63)) & 1ull) {
            float2 bx = sbox[r];
            if (bx.x > -10.0f && bx.y < 10.0f) {
                int n = sid[r];
                float* o = outb + (size_t)n * 3;
                o[0] = bx.x;
                o[1] = bx.y;
                o[2] = ssc[r];
            }
        }
    }
}

// ---- Clock calibration: 16 independent FMA chains x 3750 iters = 60000
// VALU wave-instrs ~= 120k cycles issue-bound for a lone wave64.
// dispatch dur_us => shader clock. Never writes in practice (guard false).
__global__ void spin_kernel(float* ws) {
    float a[16];
#pragma unroll
    for (int k = 0; k < 16; ++k)
        a[k] = (float)(k + 1) + (float)threadIdx.x * 1e-20f;
    for (int i = 0; i < 3750; ++i) {
#pragma unroll
        for (int k = 0; k < 16; ++k)
            a[k] = fmaf(a[k], 0.9999999f, 1.0e-7f);
    }
    float s = 0.f;
#pragma unroll
    for (int k = 0; k < 16; ++k) s += a[k];
    if (s == 1234.56789f && ws) ws[0] = s;   // opaque, never taken
}

extern "C" void kernel_launch(void* const* d_in, const int* in_sizes, int n_in,
                              void* d_out, int out_size, void* d_ws, size_t ws_size,
                              hipStream_t stream) {
    const float* loc  = (const float*)d_in[0];  // localizations (8,2048,2)
    const float* cls  = (const float*)d_in[1];  // classifications (8,2048,5)
    const float* defs = (const float*)d_in[2];  // localizations_default (2048,2)
    float* out = (float*)d_out;                 // (8,4,2048,3) fp32
    det_kernel<<<32, BLOCK, 0, stream>>>(loc, cls, defs, out);
    spin_kernel<<<1, 64, 0, stream>>>((float*)d_ws);   // clock calibration probe
}

// Round 8
// 199.473 us; speedup vs baseline: 1.1987x; 1.1987x over previous
//
#include <hip/hip_runtime.h>
#include <math.h>

#define N_ANCHORS 2048
#define BLOCK 512
#define THRESH 0.3f
#define OVERLAP 0.5f

// Manual LDS pool: stage A (compacted, anchor order) then stage B (sorted
// order) alias the same bytes; handoff goes through registers + a barrier.
#define OFF_CSC   0        // float[2052]   stage A  (8208 B)
#define OFF_CBX   8208     // float2[2048]  stage A  (16384 B)
#define OFF_CID   24592    // ushort[2048]  stage A  (4096 B)
#define OFF_SBOX  0        // float2[2112]  stage B  (16896 B)
#define OFF_SSC   16896    // float[2048]   stage B  (8192 B)
#define OFF_SID   25088    // ushort[2048]  stage B  (4096 B)
#define POOL_SZ   29184

#define TRI(k, w) ((k) * ((k) + 1) / 2 + (w))   // triangular row storage

// Exact IoU>0.5 predicate without division in the common path.
// t = 0.5*u is EXACT (u >= 1e-12 is normal; *0.5 = exponent decrement).
//  inter <= t            -> quotient <= 0.5 -> pred false      (exact)
//  inter >  t*(1+2^-24)  -> fl(inter/u) > 0.5 -> pred true     (exact)
//  boundary half-ulp window -> take the true division          (exact)
#define IOU_GT_HALF(bS, bE, uS, uE, ulen, res) do {                       \
    float _in = fminf(uE, bE) - fmaxf(uS, bS);                            \
    _in = fmaxf(_in, 0.0f);                                               \
    float _un = (bE - bS) + ulen - _in;                                   \
    float _u  = fmaxf(_un, 1e-12f);                                       \
    float _t  = 0.5f * _u;                                                \
    bool _g = _in > _t;                                                   \
    if (_g && _in <= _t * 1.00000012f) _g = (_in / _u) > 0.5f;            \
    res = _g;                                                             \
} while (0)

__global__ __launch_bounds__(BLOCK) void det_kernel(
    const float* __restrict__ loc,    // (8, 2048, 2)
    const float* __restrict__ cls,    // (8, 2048, 5)
    const float* __restrict__ defs,   // (2048, 2)
    float* __restrict__ out)          // (8, 4, 2048, 3)
{
#pragma clang fp contract(off)
    const int tid  = threadIdx.x;
    const int lane = tid & 63;
    const int wid  = tid >> 6;        // 0..7
    const int bc   = blockIdx.x;      // 0..31
    const int b    = bc >> 2;
    const int c    = bc & 3;          // softmax component c+1

    __shared__ __align__(16) unsigned char pool[POOL_SZ];
    // transposed: suprowT[w*512 + u] = word w of box u's suppression row
    __shared__ __align__(16) unsigned long long suprowT[8 * 512];   // 32 KB
    __shared__ unsigned long long keptg[32];    // kept bits, global sorted pos
    __shared__ unsigned long long s_deadw[8];   // cross-superchunk dead words
    __shared__ int s_wsum[8], s_woff[8], s_V;

    float*          csc  = (float*)(pool + OFF_CSC);
    float2*         cbx  = (float2*)(pool + OFF_CBX);
    unsigned short* cid  = (unsigned short*)(pool + OFF_CID);
    float2*         sbox = (float2*)(pool + OFF_SBOX);
    float*          ssc  = (float*)(pool + OFF_SSC);
    unsigned short* sid  = (unsigned short*)(pool + OFF_SID);

    // ---- Phase 0: zero output (fire-and-forget; barriers drain vmcnt) ----
    float* const outb = out + (size_t)bc * N_ANCHORS * 3;
    {
        float4 z4 = make_float4(0.f, 0.f, 0.f, 0.f);
        float4* ob4 = (float4*)outb;
        for (int i = tid; i < (N_ANCHORS * 3) / 4; i += BLOCK) ob4[i] = z4;
    }
    if (tid < 32) keptg[tid] = 0ull;

    // ---- Phase 1: float4 loads + softmax + decode, 4 consecutive anchors ----
    const int base = tid * 4;
    float c20[20], l8v[8], d8v[8];
    {
        const float4* cp4 = (const float4*)(cls + ((size_t)b * N_ANCHORS + base) * 5);
#pragma unroll
        for (int q = 0; q < 5; ++q) ((float4*)c20)[q] = cp4[q];
        const float4* lp4 = (const float4*)(loc + ((size_t)b * N_ANCHORS + base) * 2);
        ((float4*)l8v)[0] = lp4[0]; ((float4*)l8v)[1] = lp4[1];
        const float4* dp4 = (const float4*)(defs + (size_t)base * 2);
        ((float4*)d8v)[0] = dp4[0]; ((float4*)d8v)[1] = dp4[1];
    }
    float sc4[4], bs4[4], be4[4];
    int vmask = 0, cnt = 0;
#pragma unroll
    for (int k = 0; k < 4; ++k) {
        float x0 = c20[5*k+0], x1 = c20[5*k+1], x2 = c20[5*k+2],
              x3 = c20[5*k+3], x4 = c20[5*k+4];
        float m  = fmaxf(fmaxf(fmaxf(fmaxf(x0, x1), x2), x3), x4);
        float e0 = expf(x0 - m), e1 = expf(x1 - m), e2 = expf(x2 - m),
              e3 = expf(x3 - m), e4 = expf(x4 - m);
        float sum = e0 + e1 + e2 + e3 + e4;
        float ec  = (c == 0) ? e1 : (c == 1) ? e2 : (c == 2) ? e3 : e4;
        float score = ec / sum;
        float l0 = l8v[2*k], l1 = l8v[2*k+1];
        float d0 = d8v[2*k], d1 = d8v[2*k+1];
        float cc = d0 + l0 * d1;
        float w  = d1 * expf(l1);
        sc4[k] = score;
        bs4[k] = cc - 0.5f * w;
        be4[k] = cc + 0.5f * w;
        if (score > THRESH) { vmask |= (1 << k); cnt++; }
    }

    // ---- ordered compaction (compacted order == anchor order) ----
    int inc = cnt;
    for (int d = 1; d < 64; d <<= 1) {
        int v = __shfl_up(inc, d);
        if (lane >= d) inc += v;
    }
    if (lane == 63) s_wsum[wid] = inc;
    __syncthreads();
    if (tid == 0) {
        int o = 0;
        for (int w = 0; w < 8; ++w) { s_woff[w] = o; o += s_wsum[w]; }
        s_V = o;
    }
    __syncthreads();
    {
        int off = s_woff[wid] + (inc - cnt);
#pragma unroll
        for (int k = 0; k < 4; ++k) {
            if (vmask & (1 << k)) {
                csc[off] = sc4[k];
                cbx[off] = make_float2(bs4[k], be4[k]);
                cid[off] = (unsigned short)(base + k);
                off++;
            }
        }
    }
    __syncthreads();
    const int V = s_V;
    const int SCend = ((V + 511) >> 9) << 9;   // pad to super-chunk boundary
    if (tid < 4) csc[V + tid] = -INFINITY;     // pad for float4 rank stream
    __syncthreads();

    // ---- Phase 2: counting rank (score desc, anchor-order asc on ties) ----
    // Gather to REGISTERS before stage-B overwrites stage-A bytes.
    // 4-batched LDS reads keep 4 loads in flight.
#define RANKCMP(sv, ib, off2, mref, rref)                                   \
    rref += ((sv) > (mref) || ((sv) == (mref) && (ib) + (off2) < pcmp)) ? 1 : 0;
    int rr[4]; float2 rb[4]; float rs[4]; int ridv[4]; int nown = 0;
    if (V <= 512) {
        if (tid < 256) {
            int   p0 = tid, p1 = tid + 256;
            bool  a0 = p0 < V, a1 = p1 < V;
            float m0 = a0 ? csc[p0] : INFINITY;
            float m1 = a1 ? csc[p1] : INFINITY;
            int   r0 = 0, r1 = 0;
            const float4* cs4 = (const float4*)csc;
            const int n4 = (V + 3) >> 2;
            int i4 = 0;
            for (; i4 + 4 <= n4; i4 += 4) {
                float4 q0 = cs4[i4+0], q1 = cs4[i4+1], q2 = cs4[i4+2], q3 = cs4[i4+3];
                int ib = i4 << 2;
                { int pcmp = p0;
                  RANKCMP(q0.x, ib, 0,  m0, r0) RANKCMP(q0.y, ib, 1,  m0, r0)
                  RANKCMP(q0.z, ib, 2,  m0, r0) RANKCMP(q0.w, ib, 3,  m0, r0)
                  RANKCMP(q1.x, ib, 4,  m0, r0) RANKCMP(q1.y, ib, 5,  m0, r0)
                  RANKCMP(q1.z, ib, 6,  m0, r0) RANKCMP(q1.w, ib, 7,  m0, r0)
                  RANKCMP(q2.x, ib, 8,  m0, r0) RANKCMP(q2.y, ib, 9,  m0, r0)
                  RANKCMP(q2.z, ib, 10, m0, r0) RANKCMP(q2.w, ib, 11, m0, r0)
                  RANKCMP(q3.x, ib, 12, m0, r0) RANKCMP(q3.y, ib, 13, m0, r0)
                  RANKCMP(q3.z, ib, 14, m0, r0) RANKCMP(q3.w, ib, 15, m0, r0) }
                { int pcmp = p1;
                  RANKCMP(q0.x, ib, 0,  m1, r1) RANKCMP(q0.y, ib, 1,  m1, r1)
                  RANKCMP(q0.z, ib, 2,  m1, r1) RANKCMP(q0.w, ib, 3,  m1, r1)
                  RANKCMP(q1.x, ib, 4,  m1, r1) RANKCMP(q1.y, ib, 5,  m1, r1)
                  RANKCMP(q1.z, ib, 6,  m1, r1) RANKCMP(q1.w, ib, 7,  m1, r1)
                  RANKCMP(q2.x, ib, 8,  m1, r1) RANKCMP(q2.y, ib, 9,  m1, r1)
                  RANKCMP(q2.z, ib, 10, m1, r1) RANKCMP(q2.w, ib, 11, m1, r1)
                  RANKCMP(q3.x, ib, 12, m1, r1) RANKCMP(q3.y, ib, 13, m1, r1)
                  RANKCMP(q3.z, ib, 14, m1, r1) RANKCMP(q3.w, ib, 15, m1, r1) }
            }
            for (; i4 < n4; ++i4) {
                float4 s4 = cs4[i4];
                int ib = i4 << 2;
                { int pcmp = p0;
                  RANKCMP(s4.x, ib, 0, m0, r0) RANKCMP(s4.y, ib, 1, m0, r0)
                  RANKCMP(s4.z, ib, 2, m0, r0) RANKCMP(s4.w, ib, 3, m0, r0) }
                { int pcmp = p1;
                  RANKCMP(s4.x, ib, 0, m1, r1) RANKCMP(s4.y, ib, 1, m1, r1)
                  RANKCMP(s4.z, ib, 2, m1, r1) RANKCMP(s4.w, ib, 3, m1, r1) }
            }
            if (a0) { rr[nown] = r0; rb[nown] = cbx[p0]; rs[nown] = m0; ridv[nown] = cid[p0]; nown++; }
            if (a1) { rr[nown] = r1; rb[nown] = cbx[p1]; rs[nown] = m1; ridv[nown] = cid[p1]; nown++; }
        }
    } else {
        for (int p = tid; p < V; p += BLOCK) {
            float s = csc[p];
            int r = 0;
            const float4* cs4 = (const float4*)csc;
            const int n4 = (V + 3) >> 2;
            for (int i4 = 0; i4 < n4; ++i4) {
                float4 s4 = cs4[i4];
                int ib = i4 << 2;
                int pcmp = p;
                RANKCMP(s4.x, ib, 0, s, r) RANKCMP(s4.y, ib, 1, s, r)
                RANKCMP(s4.z, ib, 2, s, r) RANKCMP(s4.w, ib, 3, s, r)
            }
            rr[nown] = r; rb[nown] = cbx[p]; rs[nown] = s; ridv[nown] = cid[p]; nown++;
        }
    }
#undef RANKCMP
    __syncthreads();   // all stage-A reads done
    for (int q = 0; q < nown; ++q) {
        sbox[rr[q]] = rb[q];
        ssc[rr[q]]  = rs[q];
        sid[rr[q]]  = (unsigned short)ridv[q];
    }
    for (int i = V + tid; i < SCend; i += BLOCK)
        sbox[i] = make_float2(1e30f, 1e30f);   // inert pad (IoU == 0, incl. pad-pad)
    __syncthreads();

    // ---- Phase 3: super-chunks of 512 sorted boxes (one pass when V<=512) ----
    for (int s0 = 0; s0 < V; s0 += 512) {
        const int scn = (V - s0 < 512) ? (V - s0) : 512;
        const int i   = tid;                 // box index within super-chunk
        float2 my = sbox[s0 + i];            // pads are inert
        float  ml = my.y - my.x;

        // (a) dead from earlier super-chunks' kept (no-op when s0 == 0)
        bool dead = false;
        const int ew_n = s0 >> 6;
        for (int ew = 0; ew < ew_n; ++ew) {
            unsigned long long kw = keptg[ew];   // wave-uniform
            if (kw) {
                const float4* sb4 = (const float4*)(sbox + (ew << 6));
#pragma unroll
                for (int jj = 0; jj < 32; ++jj) {
                    float4 bp = sb4[jj];
                    bool g0, g1;
                    IOU_GT_HALF(bp.x, bp.y, my.x, my.y, ml, g0);
                    IOU_GT_HALF(bp.z, bp.w, my.x, my.y, ml, g1);
                    unsigned long long bits = kw >> (2 * jj);
                    dead |= g0 && ((bits & 1ull) != 0ull);
                    dead |= g1 && ((bits & 2ull) != 0ull);
                }
            }
        }
        {
            unsigned long long db = __ballot(dead && (i < scn));
            if (lane == 0) s_deadw[wid] = db;
        }

        // (b) build suppression rows, TRANSPOSED, REBALANCED round-robin.
        // Off-diagonal units (w<k): j0 < u always -> no index compare.
        {
            int t = 0;
#pragma unroll
            for (int k = 0; k < 8; ++k) {
#pragma unroll
                for (int w = 0; w <= k; ++w, ++t) {
                    if ((t & 7) == wid) {
                        const int u = (k << 6) + lane;   // row this lane builds
                        float2 ub = sbox[s0 + u];        // lane-distinct b64
                        float  ul = ub.y - ub.x;
                        const float4* sb4 = (const float4*)(sbox + s0 + (w << 6));
                        unsigned long long word = 0ull;
                        if (w == k) {                    // diagonal: mask j<u
#pragma unroll
                            for (int jj = 0; jj < 32; ++jj) {
                                float4 bp = sb4[jj];
                                bool g0, g1;
                                IOU_GT_HALF(bp.x, bp.y, ub.x, ub.y, ul, g0);
                                IOU_GT_HALF(bp.z, bp.w, ub.x, ub.y, ul, g1);
                                if (g0 && 2 * jj     < lane) word |= (1ull << (2 * jj));
                                if (g1 && 2 * jj + 1 < lane) word |= (1ull << (2 * jj + 1));
                            }
                        } else {                         // off-diagonal: all j<u
#pragma unroll
                            for (int jj = 0; jj < 32; ++jj) {
                                float4 bp = sb4[jj];
                                bool g0, g1;
                                IOU_GT_HALF(bp.x, bp.y, ub.x, ub.y, ul, g0);
                                IOU_GT_HALF(bp.z, bp.w, ub.x, ub.y, ul, g1);
                                if (g0) word |= (1ull << (2 * jj));
                                if (g1) word |= (1ull << (2 * jj + 1));
                            }
                        }
                        suprowT[(w << 9) + u] = word;
                    }
                }
            }
        }
        __syncthreads();

        // (c) wave 0: register-resident greedy fixpoint. No LDS, no barriers
        // in the loop; 2 ballots per DAG level.
        if (wid == 0) {
            unsigned long long row[36];
#pragma unroll
            for (int k = 0; k < 8; ++k)
#pragma unroll
                for (int w = 0; w <= k; ++w)
                    row[TRI(k, w)] = suprowT[(w << 9) + (k << 6) + lane];
            unsigned long long sdead[8];
#pragma unroll
            for (int w = 0; w < 8; ++w) sdead[w] = s_deadw[w];

            unsigned long long kv[8];
#pragma unroll
            for (int w = 0; w < 8; ++w) {
                kv[w] = 0ull;
                if ((w << 6) < scn) {
                    bool dl = ((sdead[w] >> lane) & 1ull) != 0ull;
#pragma unroll
                    for (int w2 = 0; w2 < w; ++w2)
                        dl |= (row[TRI(w, w2)] & kv[w2]) != 0ull;
                    const unsigned long long rself = row[TRI(w, w)];
                    int rem = scn - (w << 6);
                    unsigned long long valid =
                        (rem >= 64) ? ~0ull : ((1ull << rem) - 1ull);
                    unsigned long long cand = valid & ~__ballot(dl);
                    unsigned long long kw = 0ull;
                    while (cand) {
                        unsigned long long suppw = __ballot((rself & cand) != 0ull);
                        unsigned long long nk = cand & ~suppw;
                        if (!nk) nk = cand & (~cand + 1ull);  // acyclic: unreachable
                        kw |= nk;
                        unsigned long long ddw = __ballot((rself & nk) != 0ull);
                        cand &= ~(nk | ddw);
                    }
                    kv[w] = kw;
                }
            }
            if (lane == 0) {
#pragma unroll
                for (int w = 0; w < 8; ++w) keptg[(s0 >> 6) + w] |= kv[w];
            }
        }
        __syncthreads();
    }

    // ---- Phase 4: scatter kept (in_range applied at output only) ----
    for (int r = tid; r < V; r += BLOCK) {
        if ((keptg[r >> 6] >> (r & 63)) & 1ull) {
            float2 bx = sbox[r];
            if (bx.x > -10.0f && bx.y < 10.0f) {
                int n = sid[r];
                float* o = outb + (size_t)n * 3;
                o[0] = bx.x;
                o[1] = bx.y;
                o[2] = ssc[r];
            }
        }
    }
}

extern "C" void kernel_launch(void* const* d_in, const int* in_sizes, int n_in,
                              void* d_out, int out_size, void* d_ws, size_t ws_size,
                              hipStream_t stream) {
    const float* loc  = (const float*)d_in[0];  // localizations (8,2048,2)
    const float* cls  = (const float*)d_in[1];  // classifications (8,2048,5)
    const float* defs = (const float*)d_in[2];  // localizations_default (2048,2)
    float* out = (float*)d_out;                 // (8,4,2048,3) fp32
    det_kernel<<<32, BLOCK, 0, stream>>>(loc, cls, defs, out);
}